// Round 4
// baseline (574.957 us; speedup 1.0000x reference)
//
#include <hip/hip_runtime.h>

typedef unsigned short u16;
typedef unsigned int u32;
typedef __attribute__((ext_vector_type(8))) short short8;
typedef __attribute__((ext_vector_type(4))) float f32x4;

#define NB 4096
#define LDIM 8192
#define HDIM 256
#define NEXP 3
#define NCH 8
#define BK 32

__device__ inline u16 f2bf(float f) {
  u32 u = __float_as_uint(f);
  u += 0x7FFFu + ((u >> 16) & 1u);
  return (u16)(u >> 16);
}
__device__ inline u32 pack2(float x, float y) {
  return (u32)f2bf(x) | ((u32)f2bf(y) << 16);
}
__device__ inline void gll16(const void* g, void* l) {
  __builtin_amdgcn_global_load_lds((const __attribute__((address_space(1))) void*)g,
                                   (__attribute__((address_space(3))) void*)l, 16, 0, 0);
}

// ---------------- Kernel 1: per-channel quantile thresholds ----------------
__global__ void thresh_kernel(const float* __restrict__ q, const int* __restrict__ ch,
                              float* __restrict__ uq_th, float* __restrict__ lq_th) {
  int c = blockIdx.x;
  int tid = threadIdx.x;
  __shared__ float vals[1536];
  __shared__ int oidx[1536];
  __shared__ int n_sh;
  if (tid == 0) n_sh = 0;
  __syncthreads();
  for (int i = tid; i < NB; i += 256) {
    if (ch[i] == c) {
      int p = atomicAdd(&n_sh, 1);
      if (p < 1536) { vals[p] = q[i]; oidx[p] = i; }
    }
  }
  __syncthreads();
  int n = n_sh < 1536 ? n_sh : 1536;
  float nf = (float)n_sh;
  float au = ceilf((nf + 1.0f) * 0.9f) / nf;
  float pu = (au > 1.0f) ? 0.9f : au;
  int iu = (int)floorf(pu * (nf - 1.0f));
  float al = floorf((nf + 1.0f) * 0.1f) / nf;
  float pl = (al < 0.0f) ? 0.1f : al;
  int il = (int)floorf(pl * (nf - 1.0f));
  for (int e = tid; e < n; e += 256) {
    float v = vals[e];
    int oi = oidx[e];
    int r = 0;
    for (int m = 0; m < n; ++m) {
      float vm = vals[m];
      if (vm < v || (vm == v && oidx[m] < oi)) r++;
    }
    if (r == iu) uq_th[c] = v;
    if (r == il) lq_th[c] = v;
  }
}

// ---------------- Kernel 2: group assignment + expert index lists ----------------
__global__ void group_kernel(const float* __restrict__ q, const int* __restrict__ ch,
                             const float* __restrict__ uq_th, const float* __restrict__ lq_th,
                             int* __restrict__ group, int* __restrict__ cnt, int* __restrict__ idxl) {
  int b = blockIdx.x * 256 + threadIdx.x;
  if (b >= NB) return;
  float qq = q[b];
  int c = ch[b];
  int g = (qq <= lq_th[c]) ? 2 : ((qq >= uq_th[c]) ? 0 : 1);
  group[b] = g;
  int pos = atomicAdd(&cnt[g], 1);
  idxl[g * NB + pos] = b;
}

// ---------------- Kernel 3: v[k][h] = W2[k][h][:] . Wh[k][:] ----------------
__global__ void v_kernel(const float* __restrict__ W2, const float* __restrict__ Wh,
                         float* __restrict__ v) {
  int wv = blockIdx.x * 4 + (threadIdx.x >> 6);  // 0..767
  int lane = threadIdx.x & 63;
  int k = wv >> 8, h = wv & 255;
  const float4* w2 = (const float4*)(W2 + ((size_t)k * HDIM + h) * LDIM);
  const float4* wh = (const float4*)(Wh + (size_t)k * LDIM);
  float s = 0.f;
  for (int i = lane; i < LDIM / 4; i += 64) {
    float4 a = w2[i], b = wh[i];
    s += a.x * b.x + a.y * b.y + a.z * b.z + a.w * b.w;
  }
  for (int off = 32; off; off >>= 1) s += __shfl_down(s, off);
  if (lane == 0) v[k * HDIM + h] = s;
}

// ---------------- Kernel 3b: cbias[k] = b2[k].Wh[k] + bh[k] ----------------
__global__ void cbias_kernel(const float* __restrict__ b2, const float* __restrict__ Wh,
                             const float* __restrict__ bh, float* __restrict__ cbias) {
  int k = threadIdx.x >> 6, lane = threadIdx.x & 63;
  float s = 0.f;
  for (int l = lane; l < LDIM; l += 64) s += b2[k * LDIM + l] * Wh[k * LDIM + l];
  for (int off = 32; off; off >>= 1) s += __shfl_down(s, off);
  if (lane == 0) cbias[k] = s + bh[k];
}

// ---------------- Kernel 4: W1 (K,L,H) f32 -> W1t (K,H,L) bf16 ----------------
__global__ void transpose_kernel(const float* __restrict__ W1, u16* __restrict__ W1t) {
  __shared__ float tile[64][65];
  int k = blockIdx.z;
  int l0 = blockIdx.x * 64;
  int h0 = blockIdx.y * 64;
  int t = threadIdx.x;
  const float* src = W1 + (size_t)k * LDIM * HDIM + (size_t)l0 * HDIM + h0;
  u16* dst = W1t + (size_t)k * HDIM * LDIM + (size_t)h0 * LDIM + l0;
  int hr = t & 63, lr = t >> 6;
#pragma unroll
  for (int p = 0; p < 16; ++p) {
    int l = p * 4 + lr;
    tile[l][hr] = src[(size_t)l * HDIM + hr];
  }
  __syncthreads();
  int cw = t & 7, hw = t >> 3;
#pragma unroll
  for (int p = 0; p < 2; ++p) {
    int h = p * 32 + hw;
    short8 v8;
#pragma unroll
    for (int j = 0; j < 8; ++j) v8[j] = (short)f2bf(tile[cw * 8 + j][h]);
    *(short8*)&dst[(size_t)h * LDIM + cw * 8] = v8;
  }
}

// ---------------- Kernel 5: gathered K-split GEMM -> part[s][b][h] ----------------
// 64x64 tile, BK=32, LDS 16.6 KB -> up to 8 blocks/CU. Swizzle: chunk ^= (row>>1)&3.
__global__ void __launch_bounds__(256) gemm_kernel(
    const float* __restrict__ z, const u16* __restrict__ W1t,
    const int* __restrict__ idxl, const int* __restrict__ cnt,
    float* __restrict__ part, int nsl, int nt) {
  int zid = blockIdx.z;
  int kexp = zid / nsl, s = zid - kexp * nsl;
  int nk = cnt[kexp];
  int rowbase = blockIdx.x * 64;
  if (rowbase >= nk) return;
  int h0 = blockIdx.y * 64;
  int tid = threadIdx.x;
  int lane = tid & 63, wv = tid >> 6;

  __shared__ __align__(16) u16 As[2][2048];
  __shared__ __align__(16) u16 Bs[2][2048];
  __shared__ int sidx[64];

  const int* idxk = idxl + kexp * NB;
  if (tid < 64) {
    int p = rowbase + tid;
    sidx[tid] = idxk[p < nk ? p : nk - 1];
  }

  // A staging: thread owns (row = tid>>2, chunk kg = tid&3) -> 8 f32 = 32 B
  int row = tid >> 2, kg = tid & 3;
  int p0 = rowbase + row; if (p0 > nk - 1) p0 = nk - 1;
  int kslice = nt * BK;
  size_t kbase = (size_t)s * kslice;
  const float* zr = z + (size_t)idxk[p0] * LDIM + kbase + kg * 8;
  int sch = kg ^ ((row >> 1) & 3);               // swizzled chunk (involution)
  int swA = row * BK + sch * 8;                  // u16 offset for ds_write_b128

  // B via global_load_lds: linear dest (byte = tid*16), inverse-swizzled source.
  // dest row = tid>>2, dest chunk = tid&3 -> source chunk = (tid&3)^((row>>1)&3) = sch
  const u16* bsrc = W1t + ((size_t)kexp * HDIM + h0 + row) * LDIM + kbase + sch * 8;

  int fr = lane & 15, kgl = (lane >> 4) * 8;     // k-offset 0,8,16,24
  int kc = kgl >> 3;                             // chunk index of this lane's k-group
  int wr = (wv >> 1) * 32, wc = (wv & 1) * 32;
  int ra0 = wr + fr, ra1 = ra0 + 16, ca0 = wc + fr, ca1 = ca0 + 16;
  int oA0 = ra0 * BK + (kc ^ ((ra0 >> 1) & 3)) * 8;
  int oA1 = ra1 * BK + (kc ^ ((ra1 >> 1) & 3)) * 8;
  int oB0 = ca0 * BK + (kc ^ ((ca0 >> 1) & 3)) * 8;
  int oB1 = ca1 * BK + (kc ^ ((ca1 >> 1) & 3)) * 8;

  f32x4 acc[2][2] = {};
  float4 a0, a1;

  // prologue: stage tile 0 into buffer 0
  gll16(bsrc, (char*)&Bs[0][0] + wv * 1024);
  a0 = *(const float4*)(zr);
  a1 = *(const float4*)(zr + 4);
  {
    uint4 pa;
    pa.x = pack2(a0.x, a0.y); pa.y = pack2(a0.z, a0.w);
    pa.z = pack2(a1.x, a1.y); pa.w = pack2(a1.z, a1.w);
    *(uint4*)&As[0][swA] = pa;
  }
  __syncthreads();

  int cur = 0;
  for (int t = 0; t < nt; ++t) {
    int nxt = cur ^ 1;
    bool pre = (t + 1 < nt);
    if (pre) {
      int off = (t + 1) * BK;
      gll16(bsrc + off, (char*)&Bs[nxt][0] + wv * 1024);
      a0 = *(const float4*)(zr + off);
      a1 = *(const float4*)(zr + off + 4);
    }
    {
      const u16* Ac = &As[cur][0];
      const u16* Bc = &Bs[cur][0];
      short8 af0 = *(const short8*)&Ac[oA0];
      short8 af1 = *(const short8*)&Ac[oA1];
      short8 bf0 = *(const short8*)&Bc[oB0];
      short8 bf1 = *(const short8*)&Bc[oB1];
      acc[0][0] = __builtin_amdgcn_mfma_f32_16x16x32_bf16(af0, bf0, acc[0][0], 0, 0, 0);
      acc[0][1] = __builtin_amdgcn_mfma_f32_16x16x32_bf16(af0, bf1, acc[0][1], 0, 0, 0);
      acc[1][0] = __builtin_amdgcn_mfma_f32_16x16x32_bf16(af1, bf0, acc[1][0], 0, 0, 0);
      acc[1][1] = __builtin_amdgcn_mfma_f32_16x16x32_bf16(af1, bf1, acc[1][1], 0, 0, 0);
    }
    if (pre) {
      uint4 pa;
      pa.x = pack2(a0.x, a0.y); pa.y = pack2(a0.z, a0.w);
      pa.z = pack2(a1.x, a1.y); pa.w = pack2(a1.z, a1.w);
      *(uint4*)&As[nxt][swA] = pa;
    }
    __syncthreads();
    cur = nxt;
  }

  // store raw partial tile to part[s][b][h] (unique addresses, no atomics)
  float* pdst = part + (size_t)s * NB * HDIM;
#pragma unroll
  for (int rb = 0; rb < 2; ++rb)
#pragma unroll
    for (int cb = 0; cb < 2; ++cb)
#pragma unroll
      for (int i = 0; i < 4; ++i) {
        int r = wr + rb * 16 + (lane >> 4) * 4 + i;
        int col = wc + cb * 16 + fr;
        if (rowbase + r < nk)
          pdst[(size_t)sidx[r] * HDIM + h0 + col] = acc[rb][cb][i];
      }
}

// ---------------- Kernel 5b: epilogue — sum partials, gelu, dot(v) -> logits ----------------
__global__ void ep_kernel(const float* __restrict__ part, const float* __restrict__ b1,
                          const float* __restrict__ v, const int* __restrict__ group,
                          float* __restrict__ logits, int nsl) {
  int b = blockIdx.x;
  int t = threadIdx.x;
  int g = group[b];
  size_t o = (size_t)b * HDIM + t;
  const size_t SS = (size_t)NB * HDIM;
  float x = b1[g * HDIM + t];
  for (int i = 0; i < nsl; ++i) x += part[o + i * SS];
  float ge = 0.5f * x * (1.0f + erff(x * 0.70710678118654752f));
  float y = ge * v[g * HDIM + t];
#pragma unroll
  for (int off = 32; off; off >>= 1) y += __shfl_down(y, off);
  __shared__ float red[4];
  int lane = t & 63, wv = t >> 6;
  if (lane == 0) red[wv] = y;
  __syncthreads();
  if (t == 0) logits[b] = red[0] + red[1] + red[2] + red[3];
}

// ---------------- Kernel 6: per-channel softmax * q ----------------
__global__ void softmax_kernel(const float* __restrict__ logits, const float* __restrict__ cbias,
                               const int* __restrict__ group, const float* __restrict__ q,
                               const int* __restrict__ ch, float* __restrict__ out) {
  int c = blockIdx.x;
  int tid = threadIdx.x;
  __shared__ float red[256];
  float m = -3.4e38f;
  for (int i = tid; i < NB; i += 256)
    if (ch[i] == c) {
      float x = logits[i] + cbias[group[i]];
      m = fmaxf(m, x);
    }
  red[tid] = m;
  __syncthreads();
  for (int s = 128; s > 0; s >>= 1) {
    if (tid < s) red[tid] = fmaxf(red[tid], red[tid + s]);
    __syncthreads();
  }
  m = red[0];
  __syncthreads();
  float sum = 0.f;
  for (int i = tid; i < NB; i += 256)
    if (ch[i] == c) sum += expf(logits[i] + cbias[group[i]] - m);
  red[tid] = sum;
  __syncthreads();
  for (int s = 128; s > 0; s >>= 1) {
    if (tid < s) red[tid] += red[tid + s];
    __syncthreads();
  }
  float S = red[0];
  for (int i = tid; i < NB; i += 256)
    if (ch[i] == c) out[i] = q[i] * expf(logits[i] + cbias[group[i]] - m) / S;
}

extern "C" void kernel_launch(void* const* d_in, const int* in_sizes, int n_in,
                              void* d_out, int out_size, void* d_ws, size_t ws_size,
                              hipStream_t stream) {
  const float* z  = (const float*)d_in[0];
  const float* q  = (const float*)d_in[1];
  const int*   ch = (const int*)d_in[2];
  const float* W1 = (const float*)d_in[3];
  const float* b1 = (const float*)d_in[4];
  const float* W2 = (const float*)d_in[5];
  const float* b2 = (const float*)d_in[6];
  const float* Wh = (const float*)d_in[7];
  const float* bh = (const float*)d_in[8];
  float* out = (float*)d_out;

  float* wsf    = (float*)d_ws;
  float* logits = wsf;                     // 4096 f32
  int*   cnt    = (int*)(wsf + 4096);      // 4 int
  float* uq_th  = wsf + 4100;              // 8
  float* lq_th  = wsf + 4108;              // 8
  float* cbias  = wsf + 4116;              // 4
  float* v      = wsf + 4120;              // 768
  int*   group  = (int*)(wsf + 4888);      // 4096 int
  int*   idxl   = (int*)(wsf + 8984);      // 3*4096 int
  u16*   W1t    = (u16*)(wsf + 21272);     // 3*256*8192 bf16
  float* part   = wsf + 3167000;           // nsl*4096*256 f32

  // KSPLIT=8 needs part = 33.6 MB (total ~46.2 MB of ws); fall back to 4 otherwise.
  size_t need8 = (size_t)3167000 * 4 + (size_t)8 * NB * HDIM * 4;
  int nsl = (ws_size >= need8) ? 8 : 4;
  int nt = (LDIM / nsl) / BK;  // 32 (nsl=8) or 64 (nsl=4)

  hipMemsetAsync((char*)d_ws + 4096 * 4, 0, 16, stream);  // zero cnt
  hipLaunchKernelGGL(thresh_kernel, dim3(NCH), dim3(256), 0, stream, q, ch, uq_th, lq_th);
  hipLaunchKernelGGL(group_kernel, dim3(16), dim3(256), 0, stream, q, ch, uq_th, lq_th, group, cnt, idxl);
  hipLaunchKernelGGL(v_kernel, dim3(192), dim3(256), 0, stream, W2, Wh, v);
  hipLaunchKernelGGL(cbias_kernel, dim3(1), dim3(192), 0, stream, b2, Wh, bh, cbias);
  hipLaunchKernelGGL(transpose_kernel, dim3(128, 4, 3), dim3(256), 0, stream, W1, W1t);
  hipLaunchKernelGGL(gemm_kernel, dim3(64, 4, NEXP * nsl), dim3(256), 0, stream,
                     z, W1t, idxl, cnt, part, nsl, nt);
  hipLaunchKernelGGL(ep_kernel, dim3(NB), dim3(256), 0, stream, part, b1, v, group, logits, nsl);
  hipLaunchKernelGGL(softmax_kernel, dim3(NCH), dim3(256), 0, stream, logits, cbias, group, q, ch, out);
}

// Round 8
// 564.922 us; speedup vs baseline: 1.0178x; 1.0178x over previous
//
#include <hip/hip_runtime.h>

typedef unsigned short u16;
typedef unsigned int u32;
typedef __attribute__((ext_vector_type(8))) short short8;
typedef __attribute__((ext_vector_type(4))) float f32x4;

#define NB 4096
#define LDIM 8192
#define HDIM 256
#define NEXP 3
#define NCH 8
#define BK 32
#define BM 128
#define BN 128

__device__ inline u16 f2bf(float f) {
  u32 u = __float_as_uint(f);
  u += 0x7FFFu + ((u >> 16) & 1u);
  return (u16)(u >> 16);
}
__device__ inline u32 pack2(float x, float y) {
  return (u32)f2bf(x) | ((u32)f2bf(y) << 16);
}
__device__ inline void gll16(const void* g, void* l) {
  __builtin_amdgcn_global_load_lds((const __attribute__((address_space(1))) void*)g,
                                   (__attribute__((address_space(3))) void*)l, 16, 0, 0);
}

// ---------------- Kernel 1: per-channel quantile thresholds ----------------
__global__ void thresh_kernel(const float* __restrict__ q, const int* __restrict__ ch,
                              float* __restrict__ uq_th, float* __restrict__ lq_th) {
  int c = blockIdx.x;
  int tid = threadIdx.x;
  __shared__ float vals[1536];
  __shared__ int oidx[1536];
  __shared__ int n_sh;
  if (tid == 0) n_sh = 0;
  __syncthreads();
  for (int i = tid; i < NB; i += 256) {
    if (ch[i] == c) {
      int p = atomicAdd(&n_sh, 1);
      if (p < 1536) { vals[p] = q[i]; oidx[p] = i; }
    }
  }
  __syncthreads();
  int n = n_sh < 1536 ? n_sh : 1536;
  float nf = (float)n_sh;
  float au = ceilf((nf + 1.0f) * 0.9f) / nf;
  float pu = (au > 1.0f) ? 0.9f : au;
  int iu = (int)floorf(pu * (nf - 1.0f));
  float al = floorf((nf + 1.0f) * 0.1f) / nf;
  float pl = (al < 0.0f) ? 0.1f : al;
  int il = (int)floorf(pl * (nf - 1.0f));
  for (int e = tid; e < n; e += 256) {
    float v = vals[e];
    int oi = oidx[e];
    int r = 0;
    for (int m = 0; m < n; ++m) {
      float vm = vals[m];
      if (vm < v || (vm == v && oidx[m] < oi)) r++;
    }
    if (r == iu) uq_th[c] = v;
    if (r == il) lq_th[c] = v;
  }
}

// ---------------- Kernel 2: group assignment + expert index lists ----------------
__global__ void group_kernel(const float* __restrict__ q, const int* __restrict__ ch,
                             const float* __restrict__ uq_th, const float* __restrict__ lq_th,
                             int* __restrict__ group, int* __restrict__ cnt, int* __restrict__ idxl) {
  int b = blockIdx.x * 256 + threadIdx.x;
  if (b >= NB) return;
  float qq = q[b];
  int c = ch[b];
  int g = (qq <= lq_th[c]) ? 2 : ((qq >= uq_th[c]) ? 0 : 1);
  group[b] = g;
  int pos = atomicAdd(&cnt[g], 1);
  idxl[g * NB + pos] = b;
}

// ---------------- Kernel 3: v[k][h] = W2[k][h][:] . Wh[k][:] ----------------
__global__ void v_kernel(const float* __restrict__ W2, const float* __restrict__ Wh,
                         float* __restrict__ v) {
  int wv = blockIdx.x * 4 + (threadIdx.x >> 6);  // 0..767
  int lane = threadIdx.x & 63;
  int k = wv >> 8, h = wv & 255;
  const float4* w2 = (const float4*)(W2 + ((size_t)k * HDIM + h) * LDIM);
  const float4* wh = (const float4*)(Wh + (size_t)k * LDIM);
  float s = 0.f;
  for (int i = lane; i < LDIM / 4; i += 64) {
    float4 a = w2[i], b = wh[i];
    s += a.x * b.x + a.y * b.y + a.z * b.z + a.w * b.w;
  }
  for (int off = 32; off; off >>= 1) s += __shfl_down(s, off);
  if (lane == 0) v[k * HDIM + h] = s;
}

// ---------------- Kernel 3b: cbias[k] = b2[k].Wh[k] + bh[k] ----------------
__global__ void cbias_kernel(const float* __restrict__ b2, const float* __restrict__ Wh,
                             const float* __restrict__ bh, float* __restrict__ cbias) {
  int k = threadIdx.x >> 6, lane = threadIdx.x & 63;
  float s = 0.f;
  for (int l = lane; l < LDIM; l += 64) s += b2[k * LDIM + l] * Wh[k * LDIM + l];
  for (int off = 32; off; off >>= 1) s += __shfl_down(s, off);
  if (lane == 0) cbias[k] = s + bh[k];
}

// ---------------- Kernel 4: W1 (K,L,H) f32 -> W1t (K,H,L) bf16 ----------------
__global__ void transpose_kernel(const float* __restrict__ W1, u16* __restrict__ W1t) {
  __shared__ float tile[64][65];
  int k = blockIdx.z;
  int l0 = blockIdx.x * 64;
  int h0 = blockIdx.y * 64;
  int t = threadIdx.x;
  const float* src = W1 + (size_t)k * LDIM * HDIM + (size_t)l0 * HDIM + h0;
  u16* dst = W1t + (size_t)k * HDIM * LDIM + (size_t)h0 * LDIM + l0;
  int hr = t & 63, lr = t >> 6;
#pragma unroll
  for (int p = 0; p < 16; ++p) {
    int l = p * 4 + lr;
    tile[l][hr] = src[(size_t)l * HDIM + hr];
  }
  __syncthreads();
  int cw = t & 7, hw = t >> 3;
#pragma unroll
  for (int p = 0; p < 2; ++p) {
    int h = p * 32 + hw;
    short8 v8;
#pragma unroll
    for (int j = 0; j < 8; ++j) v8[j] = (short)f2bf(tile[cw * 8 + j][h]);
    *(short8*)&dst[(size_t)h * LDIM + cw * 8] = v8;
  }
}

// ---------------- Kernel 5: gathered K-split GEMM -> part[s][b][h] ----------------
// 128x128 tile, BK=32, 4 waves each owning 64x64 (4x4 frags): 16 MFMA + 8 ds_read_b128
// per wave per barrier. LDS 33 KB dbuf. Swizzle: chunk ^= (row>>1)&3 (R4-verified, 0 conflicts).
__global__ void __launch_bounds__(256, 2) gemm_kernel(
    const float* __restrict__ z, const u16* __restrict__ W1t,
    const int* __restrict__ idxl, const int* __restrict__ cnt,
    float* __restrict__ part, int nsl, int nt) {
  int zid = blockIdx.z;
  int kexp = zid / nsl, s = zid - kexp * nsl;
  int nk = cnt[kexp];
  int rowbase = blockIdx.x * BM;
  if (rowbase >= nk) return;
  int h0 = blockIdx.y * BN;
  int tid = threadIdx.x;
  int lane = tid & 63, wv = tid >> 6;

  __shared__ __align__(16) u16 As[2][BM * BK];
  __shared__ __align__(16) u16 Bs[2][BN * BK];
  __shared__ int sidx[BM];

  const int* idxk = idxl + kexp * NB;
  if (tid < BM) {
    int p = rowbase + tid;
    sidx[tid] = idxk[p < nk ? p : nk - 1];
  }

  int kslice = nt * BK;
  size_t kbase = (size_t)s * kslice;

  // ---- A staging setup: thread owns rows {r, r+64}, 16B chunk c (8 bf16 <- 8 f32)
  int r = tid >> 2, c = tid & 3;
  int pA0 = rowbase + r;        if (pA0 > nk - 1) pA0 = nk - 1;
  int pA1 = rowbase + r + 64;   if (pA1 > nk - 1) pA1 = nk - 1;
  const float* zr0 = z + (size_t)idxk[pA0] * LDIM + kbase + c * 8;
  const float* zr1 = z + (size_t)idxk[pA1] * LDIM + kbase + c * 8;
  int swA0 = r * BK + ((c ^ ((r >> 1) & 3)) * 8);
  int swA1 = (r + 64) * BK + ((c ^ (((r + 64) >> 1) & 3)) * 8);

  // ---- B staging via global_load_lds: linear dest, inverse-swizzled source.
  // call j: dest byte = j*4096 + wv*1024 + lane*16 -> row = j*64 + wv*16 + (lane>>2),
  // chunk = lane&3 -> source chunk = (lane&3) ^ ((row>>1)&3)
  int brow0 = wv * 16 + (lane >> 2);
  int brow1 = brow0 + 64;
  const u16* bsrc0 = W1t + ((size_t)kexp * HDIM + h0 + brow0) * LDIM + kbase +
                     (size_t)(((lane & 3) ^ ((brow0 >> 1) & 3)) * 8);
  const u16* bsrc1 = W1t + ((size_t)kexp * HDIM + h0 + brow1) * LDIM + kbase +
                     (size_t)(((lane & 3) ^ ((brow1 >> 1) & 3)) * 8);

  // ---- fragment read offsets
  int fr = lane & 15, kc = lane >> 4;  // k-chunk 0..3 (8 bf16 each)
  int wr = (wv >> 1) * 64, wn = (wv & 1) * 64;
  int oA[4], oB[4];
#pragma unroll
  for (int m = 0; m < 4; ++m) {
    int ra = wr + m * 16 + fr;
    oA[m] = ra * BK + ((kc ^ ((ra >> 1) & 3)) * 8);
    int cb = wn + m * 16 + fr;
    oB[m] = cb * BK + ((kc ^ ((cb >> 1) & 3)) * 8);
  }

  f32x4 acc[4][4] = {};
  float4 a00, a01, a10, a11;

  // prologue: stage tile 0 into buffer 0
  gll16(bsrc0, (char*)&Bs[0][0] + wv * 1024);
  gll16(bsrc1, (char*)&Bs[0][0] + 4096 + wv * 1024);
  a00 = *(const float4*)(zr0);
  a01 = *(const float4*)(zr0 + 4);
  a10 = *(const float4*)(zr1);
  a11 = *(const float4*)(zr1 + 4);
  {
    uint4 p0, p1;
    p0.x = pack2(a00.x, a00.y); p0.y = pack2(a00.z, a00.w);
    p0.z = pack2(a01.x, a01.y); p0.w = pack2(a01.z, a01.w);
    p1.x = pack2(a10.x, a10.y); p1.y = pack2(a10.z, a10.w);
    p1.z = pack2(a11.x, a11.y); p1.w = pack2(a11.z, a11.w);
    *(uint4*)&As[0][swA0] = p0;
    *(uint4*)&As[0][swA1] = p1;
  }
  __syncthreads();

  int cur = 0;
  for (int t = 0; t < nt; ++t) {
    int nxt = cur ^ 1;
    bool pre = (t + 1 < nt);
    if (pre) {
      int off = (t + 1) * BK;
      gll16(bsrc0 + off, (char*)&Bs[nxt][0] + wv * 1024);
      gll16(bsrc1 + off, (char*)&Bs[nxt][0] + 4096 + wv * 1024);
      a00 = *(const float4*)(zr0 + off);
      a01 = *(const float4*)(zr0 + off + 4);
      a10 = *(const float4*)(zr1 + off);
      a11 = *(const float4*)(zr1 + off + 4);
    }
    {
      const u16* Ac = &As[cur][0];
      const u16* Bc = &Bs[cur][0];
      short8 af[4], bf[4];
#pragma unroll
      for (int m = 0; m < 4; ++m) af[m] = *(const short8*)&Ac[oA[m]];
#pragma unroll
      for (int n = 0; n < 4; ++n) bf[n] = *(const short8*)&Bc[oB[n]];
#pragma unroll
      for (int m = 0; m < 4; ++m)
#pragma unroll
        for (int n = 0; n < 4; ++n)
          acc[m][n] = __builtin_amdgcn_mfma_f32_16x16x32_bf16(af[m], bf[n], acc[m][n], 0, 0, 0);
    }
    if (pre) {
      uint4 p0, p1;
      p0.x = pack2(a00.x, a00.y); p0.y = pack2(a00.z, a00.w);
      p0.z = pack2(a01.x, a01.y); p0.w = pack2(a01.z, a01.w);
      p1.x = pack2(a10.x, a10.y); p1.y = pack2(a10.z, a10.w);
      p1.z = pack2(a11.x, a11.y); p1.w = pack2(a11.z, a11.w);
      *(uint4*)&As[nxt][swA0] = p0;
      *(uint4*)&As[nxt][swA1] = p1;
    }
    __syncthreads();
    cur = nxt;
  }

  // store raw partial tile to part[s][b][h] (unique addresses, no atomics)
  float* pdst = part + (size_t)s * NB * HDIM;
#pragma unroll
  for (int m = 0; m < 4; ++m)
#pragma unroll
    for (int i = 0; i < 4; ++i) {
      int row = wr + m * 16 + ((lane >> 4) << 2) + i;
      if (rowbase + row < nk) {
        float* rp = pdst + (size_t)sidx[row] * HDIM + h0;
#pragma unroll
        for (int n = 0; n < 4; ++n) rp[wn + n * 16 + fr] = acc[m][n][i];
      }
    }
}

// ---------------- Kernel 5b: epilogue — sum partials, gelu, dot(v) -> logits ----------------
__global__ void ep_kernel(const float* __restrict__ part, const float* __restrict__ b1,
                          const float* __restrict__ v, const int* __restrict__ group,
                          float* __restrict__ logits, int nsl) {
  int b = blockIdx.x;
  int t = threadIdx.x;
  int g = group[b];
  size_t o = (size_t)b * HDIM + t;
  const size_t SS = (size_t)NB * HDIM;
  float x = b1[g * HDIM + t];
  for (int i = 0; i < nsl; ++i) x += part[o + i * SS];
  float ge = 0.5f * x * (1.0f + erff(x * 0.70710678118654752f));
  float y = ge * v[g * HDIM + t];
#pragma unroll
  for (int off = 32; off; off >>= 1) y += __shfl_down(y, off);
  __shared__ float red[4];
  int lane = t & 63, wv = t >> 6;
  if (lane == 0) red[wv] = y;
  __syncthreads();
  if (t == 0) logits[b] = red[0] + red[1] + red[2] + red[3];
}

// ---------------- Kernel 6: per-channel softmax * q ----------------
__global__ void softmax_kernel(const float* __restrict__ logits, const float* __restrict__ cbias,
                               const int* __restrict__ group, const float* __restrict__ q,
                               const int* __restrict__ ch, float* __restrict__ out) {
  int c = blockIdx.x;
  int tid = threadIdx.x;
  __shared__ float red[256];
  float m = -3.4e38f;
  for (int i = tid; i < NB; i += 256)
    if (ch[i] == c) {
      float x = logits[i] + cbias[group[i]];
      m = fmaxf(m, x);
    }
  red[tid] = m;
  __syncthreads();
  for (int s = 128; s > 0; s >>= 1) {
    if (tid < s) red[tid] = fmaxf(red[tid], red[tid + s]);
    __syncthreads();
  }
  m = red[0];
  __syncthreads();
  float sum = 0.f;
  for (int i = tid; i < NB; i += 256)
    if (ch[i] == c) sum += expf(logits[i] + cbias[group[i]] - m);
  red[tid] = sum;
  __syncthreads();
  for (int s = 128; s > 0; s >>= 1) {
    if (tid < s) red[tid] += red[tid + s];
    __syncthreads();
  }
  float S = red[0];
  for (int i = tid; i < NB; i += 256)
    if (ch[i] == c) out[i] = q[i] * expf(logits[i] + cbias[group[i]] - m) / S;
}

extern "C" void kernel_launch(void* const* d_in, const int* in_sizes, int n_in,
                              void* d_out, int out_size, void* d_ws, size_t ws_size,
                              hipStream_t stream) {
  const float* z  = (const float*)d_in[0];
  const float* q  = (const float*)d_in[1];
  const int*   ch = (const int*)d_in[2];
  const float* W1 = (const float*)d_in[3];
  const float* b1 = (const float*)d_in[4];
  const float* W2 = (const float*)d_in[5];
  const float* b2 = (const float*)d_in[6];
  const float* Wh = (const float*)d_in[7];
  const float* bh = (const float*)d_in[8];
  float* out = (float*)d_out;

  float* wsf    = (float*)d_ws;
  float* logits = wsf;                     // 4096 f32
  int*   cnt    = (int*)(wsf + 4096);      // 4 int
  float* uq_th  = wsf + 4100;              // 8
  float* lq_th  = wsf + 4108;              // 8
  float* cbias  = wsf + 4116;              // 4
  float* v      = wsf + 4120;              // 768
  int*   group  = (int*)(wsf + 4888);      // 4096 int
  int*   idxl   = (int*)(wsf + 8984);      // 3*4096 int
  u16*   W1t    = (u16*)(wsf + 21272);     // 3*256*8192 bf16
  float* part   = wsf + 3167000;           // nsl*4096*256 f32

  size_t need8 = (size_t)3167000 * 4 + (size_t)8 * NB * HDIM * 4;
  int nsl = (ws_size >= need8) ? 8 : 4;
  int nt = (LDIM / nsl) / BK;  // 32 (nsl=8) or 64 (nsl=4)

  hipMemsetAsync((char*)d_ws + 4096 * 4, 0, 16, stream);  // zero cnt
  hipLaunchKernelGGL(thresh_kernel, dim3(NCH), dim3(256), 0, stream, q, ch, uq_th, lq_th);
  hipLaunchKernelGGL(group_kernel, dim3(16), dim3(256), 0, stream, q, ch, uq_th, lq_th, group, cnt, idxl);
  hipLaunchKernelGGL(v_kernel, dim3(192), dim3(256), 0, stream, W2, Wh, v);
  hipLaunchKernelGGL(cbias_kernel, dim3(1), dim3(192), 0, stream, b2, Wh, bh, cbias);
  hipLaunchKernelGGL(transpose_kernel, dim3(128, 4, 3), dim3(256), 0, stream, W1, W1t);
  hipLaunchKernelGGL(gemm_kernel, dim3(NB / BM, HDIM / BN, NEXP * nsl), dim3(256), 0, stream,
                     z, W1t, idxl, cnt, part, nsl, nt);
  hipLaunchKernelGGL(ep_kernel, dim3(NB), dim3(256), 0, stream, part, b1, v, group, logits, nsl);
  hipLaunchKernelGGL(softmax_kernel, dim3(NCH), dim3(256), 0, stream, logits, cbias, group, q, ch, out);
}